// Round 4
// baseline (862.966 us; speedup 1.0000x reference)
//
#include <hip/hip_runtime.h>
#include <hip/hip_bf16.h>

typedef __attribute__((ext_vector_type(8))) short short8;
typedef __attribute__((ext_vector_type(4))) float floatx4;
typedef __attribute__((ext_vector_type(16))) float f32x16;

#define B_C 4
#define NEW_C 512
#define CACHE_C 4096
#define TOTAL_C 4608
#define H_C 32
#define HKV_C 8
#define D_C 128
#define HID_C 4096
#define QKV_N 6144

__device__ __forceinline__ unsigned short f2bf(float f) {
  union { float f; unsigned u; } v; v.f = f;
  unsigned r = v.u + 0x7FFFu + ((v.u >> 16) & 1u);
  return (unsigned short)(r >> 16);
}
__device__ __forceinline__ float bf2f(unsigned short h) {
  union { unsigned u; float f; } v; v.u = ((unsigned)h) << 16; return v.f;
}
__device__ __forceinline__ unsigned pack_bf16(float lo, float hi) {
  return ((unsigned)f2bf(hi) << 16) | (unsigned)f2bf(lo);
}
__device__ __forceinline__ void gload_lds16(const unsigned short* g, unsigned short* lds) {
  __builtin_amdgcn_global_load_lds(
      (const __attribute__((address_space(1))) unsigned int*)g,
      (__attribute__((address_space(3))) unsigned int*)lds, 16, 0, 0);
}

// ---------------- RMSNorm: x f32 (2048x4096) -> hn bf16 ----------------
__global__ __launch_bounds__(256) void rmsnorm_k(const float* __restrict__ x,
                                                 const float* __restrict__ g,
                                                 unsigned short* __restrict__ hn) {
  const int row = blockIdx.x;
  const int t = threadIdx.x;
  const float4* xr = (const float4*)(x + (size_t)row * 4096);
  float4 v[4];
  float ss = 0.f;
#pragma unroll
  for (int i = 0; i < 4; ++i) {
    v[i] = xr[t + i * 256];
    ss += v[i].x * v[i].x + v[i].y * v[i].y + v[i].z * v[i].z + v[i].w * v[i].w;
  }
#pragma unroll
  for (int m = 1; m < 64; m <<= 1) ss += __shfl_xor(ss, m);
  __shared__ float red[4];
  if ((t & 63) == 0) red[t >> 6] = ss;
  __syncthreads();
  ss = red[0] + red[1] + red[2] + red[3];
  const float inv = rsqrtf(ss * (1.f / 4096.f) + 1e-6f);
  const float4* gw = (const float4*)g;
#pragma unroll
  for (int i = 0; i < 4; ++i) {
    float4 w4 = gw[t + i * 256];
    ushort4 o;
    o.x = f2bf(v[i].x * inv * w4.x);
    o.y = f2bf(v[i].y * inv * w4.y);
    o.z = f2bf(v[i].z * inv * w4.z);
    o.w = f2bf(v[i].w * inv * w4.w);
    *(ushort4*)&hn[(size_t)row * 4096 + (t + i * 256) * 4] = o;
  }
}

// ---- build wqkvT bf16 (6144 x 4096): wqkvT[n][k] = {wq|wk|wv}[k][n] ----
__global__ __launch_bounds__(256) void build_wqkvT_k(const float* __restrict__ wq,
                                                     const float* __restrict__ wk,
                                                     const float* __restrict__ wv,
                                                     unsigned short* __restrict__ out) {
  __shared__ float tile[32][33];
  const int n0 = blockIdx.x * 32, k0 = blockIdx.y * 32;
  const float* src; int ld, nc;
  if (n0 < 4096)      { src = wq; ld = 4096; nc = n0; }
  else if (n0 < 5120) { src = wk; ld = 1024; nc = n0 - 4096; }
  else                { src = wv; ld = 1024; nc = n0 - 5120; }
  const int t = threadIdx.x, r = t >> 3, cv = (t & 7) * 4;
  const float4 v = *(const float4*)&src[(size_t)(k0 + r) * ld + nc + cv];
  tile[r][cv + 0] = v.x; tile[r][cv + 1] = v.y; tile[r][cv + 2] = v.z; tile[r][cv + 3] = v.w;
  __syncthreads();
  ushort4 o;
  o.x = f2bf(tile[cv + 0][r]); o.y = f2bf(tile[cv + 1][r]);
  o.z = f2bf(tile[cv + 2][r]); o.w = f2bf(tile[cv + 3][r]);
  *(ushort4*)&out[(size_t)(n0 + r) * 4096 + k0 + cv] = o;
}

// ---- generic f32->bf16 32x32 transpose: dst[c][r] = src[r][c] ----
__global__ __launch_bounds__(256) void transpose_cvt_k(const float* __restrict__ src,
                                                       long sbs_hi, long sbs_lo, int sld,
                                                       unsigned short* __restrict__ dst,
                                                       long dbs, int dld) {
  __shared__ float tile[32][33];
  const int z = blockIdx.z;
  const long sb = (long)(z >> 3) * sbs_hi + (long)(z & 7) * sbs_lo;
  const long db = (long)z * dbs;
  const int r0 = blockIdx.y * 32, c0 = blockIdx.x * 32;
  const int t = threadIdx.x, r = t >> 3, cv = (t & 7) * 4;
  const float4 v = *(const float4*)&src[sb + (long)(r0 + r) * sld + c0 + cv];
  tile[r][cv + 0] = v.x; tile[r][cv + 1] = v.y; tile[r][cv + 2] = v.z; tile[r][cv + 3] = v.w;
  __syncthreads();
  ushort4 o;
  o.x = f2bf(tile[cv + 0][r]); o.y = f2bf(tile[cv + 1][r]);
  o.z = f2bf(tile[cv + 2][r]); o.w = f2bf(tile[cv + 3][r]);
  *(ushort4*)&dst[db + (long)(c0 + r) * dld + r0 + cv] = o;
}

// ---- u16 32x32 transpose (no convert): dst[c][r] = src[r][c] ----
__global__ __launch_bounds__(256) void transpose_u16_k(const unsigned short* __restrict__ src,
                                                       long sbs, int sld,
                                                       unsigned short* __restrict__ dst,
                                                       long dbs, int dld) {
  __shared__ unsigned short tile[32][36];
  const int z = blockIdx.z;
  const long sb = (long)z * sbs;
  const long db = (long)z * dbs;
  const int r0 = blockIdx.y * 32, c0 = blockIdx.x * 32;
  const int t = threadIdx.x, r = t >> 3, cv = (t & 7) * 4;
  const ushort4 v = *(const ushort4*)&src[sb + (long)(r0 + r) * sld + c0 + cv];
  tile[r][cv + 0] = v.x; tile[r][cv + 1] = v.y; tile[r][cv + 2] = v.z; tile[r][cv + 3] = v.w;
  __syncthreads();
  ushort4 o;
  o.x = tile[cv + 0][r]; o.y = tile[cv + 1][r]; o.z = tile[cv + 2][r]; o.w = tile[cv + 3][r];
  *(ushort4*)&dst[db + (long)(c0 + r) * dld + r0 + cv] = o;
}

// ---- k_cache f32 (B,TOTAL,HKV,D) s<CACHE -> K_all bf16 (B,HKV,TOTAL,D) ----
__global__ __launch_bounds__(256) void cvt_kcache_k(const float* __restrict__ kc,
                                                    unsigned short* __restrict__ Kall) {
  const long i = (long)blockIdx.x * 256 + threadIdx.x;  // over 4*8*4096*32 float4
  const long c = i & 31, s = (i >> 5) & 4095, h = (i >> 17) & 7, b = i >> 20;
  const float4 v = *(const float4*)&kc[((b * 4608 + s) * 8 + h) * 128 + c * 4];
  ushort4 o;
  o.x = f2bf(v.x); o.y = f2bf(v.y); o.z = f2bf(v.z); o.w = f2bf(v.w);
  *(ushort4*)&Kall[((b * 8 + h) * 4608L + s) * 128 + c * 4] = o;
}

// ---- RoPE: qkv bf16 row -> q_rope bf16, K_all bf16 (UNSCALED, R1-identical) ----
__global__ __launch_bounds__(256) void rope_k(const unsigned short* __restrict__ qkv,
                                              const float* __restrict__ cosb,
                                              const float* __restrict__ sinb,
                                              unsigned short* __restrict__ qr,
                                              unsigned short* __restrict__ Kall) {
  const int row = blockIdx.x;
  const int b = row >> 9, n = row & 511;
  const unsigned short* src = qkv + (size_t)row * QKV_N;
  const float* cr = cosb + (size_t)row * 128;
  const float* sr = sinb + (size_t)row * 128;
  const int t = threadIdx.x;
#pragma unroll
  for (int i = 0; i < 8; ++i) {  // Q: 32 heads * 64 pairs
    int pid = t + i * 256;
    int hd = pid >> 6, d = pid & 63;
    int idx = hd * 128 + d;
    float a = bf2f(src[idx]), bb = bf2f(src[idx + 64]);
    float c0 = cr[d], s0 = sr[d], c1 = cr[d + 64], s1 = sr[d + 64];
    qr[(size_t)row * 4096 + idx] = f2bf(a * c0 - bb * s0);
    qr[(size_t)row * 4096 + idx + 64] = f2bf(bb * c1 + a * s1);
  }
#pragma unroll
  for (int i = 0; i < 2; ++i) {  // K: 8 heads * 64 pairs
    int pid = t + i * 256;
    int hd = pid >> 6, d = pid & 63;
    float a = bf2f(src[4096 + hd * 128 + d]), bb = bf2f(src[4096 + hd * 128 + d + 64]);
    float c0 = cr[d], s0 = sr[d], c1 = cr[d + 64], s1 = sr[d + 64];
    long kb = ((long)(b * 8 + hd) * TOTAL_C + CACHE_C + n) * 128 + d;
    Kall[kb] = f2bf(a * c0 - bb * s0);
    Kall[kb + 64] = f2bf(bb * c1 + a * s1);
  }
}

// ---------------- GEMM: C(MxN) = A(MxK) * BT(NxK)^T, bf16 MFMA ----------------
template <int EPI>
__global__ __launch_bounds__(256) void gemm_bt(const unsigned short* __restrict__ A,
                                               const unsigned short* __restrict__ BT,
                                               unsigned short* __restrict__ Cbf,
                                               float* __restrict__ Cf,
                                               const float* __restrict__ resid,
                                               int M, int N, int K) {
  __shared__ unsigned short As[128 * 32];
  __shared__ unsigned short Bs[128 * 32];
  const int n0 = blockIdx.x * 128, m0 = blockIdx.y * 128;
  const int t = threadIdx.x, w = t >> 6, l = t & 63;
  const int l15 = l & 15, lhi = l >> 4;
  const int wm = (w >> 1) * 64, wn = (w & 1) * 64;
  floatx4 acc[4][4];
#pragma unroll
  for (int mt = 0; mt < 4; ++mt)
#pragma unroll
    for (int nt = 0; nt < 4; ++nt)
#pragma unroll
      for (int r = 0; r < 4; ++r) acc[mt][nt][r] = 0.f;

  const int c0 = w * 2, c1 = w * 2 + 1;
  const unsigned short* ga0 = A + (size_t)(m0 + c0 * 16 + (l >> 2)) * K + (l & 3) * 8;
  const unsigned short* ga1 = A + (size_t)(m0 + c1 * 16 + (l >> 2)) * K + (l & 3) * 8;
  const unsigned short* gb0 = BT + (size_t)(n0 + c0 * 16 + (l >> 2)) * K + (l & 3) * 8;
  const unsigned short* gb1 = BT + (size_t)(n0 + c1 * 16 + (l >> 2)) * K + (l & 3) * 8;
  unsigned short* lA0 = &As[c0 * 512];
  unsigned short* lA1 = &As[c1 * 512];
  unsigned short* lB0 = &Bs[c0 * 512];
  unsigned short* lB1 = &Bs[c1 * 512];

  for (int k0 = 0; k0 < K; k0 += 32) {
    gload_lds16(ga0 + k0, lA0);
    gload_lds16(ga1 + k0, lA1);
    gload_lds16(gb0 + k0, lB0);
    gload_lds16(gb1 + k0, lB1);
    __syncthreads();
    short8 af[4], bfv[4];
#pragma unroll
    for (int i = 0; i < 4; ++i) {
      af[i] = *(const short8*)&As[(wm + i * 16 + l15) * 32 + lhi * 8];
      bfv[i] = *(const short8*)&Bs[(wn + i * 16 + l15) * 32 + lhi * 8];
    }
#pragma unroll
    for (int mt = 0; mt < 4; ++mt)
#pragma unroll
      for (int nt = 0; nt < 4; ++nt)
        acc[mt][nt] = __builtin_amdgcn_mfma_f32_16x16x32_bf16(af[mt], bfv[nt], acc[mt][nt], 0, 0, 0);
    __syncthreads();
  }
#pragma unroll
  for (int mt = 0; mt < 4; ++mt)
#pragma unroll
    for (int nt = 0; nt < 4; ++nt)
#pragma unroll
      for (int r = 0; r < 4; ++r) {
        const int row = m0 + wm + mt * 16 + lhi * 4 + r;
        const int col = n0 + wn + nt * 16 + l15;
        const size_t idx = (size_t)row * N + col;
        if (EPI == 0) Cbf[idx] = f2bf(acc[mt][nt][r]);
        else Cf[idx] = acc[mt][nt][r] + resid[idx];
      }
}

// ======== Flash attention v2b: swapped-operand 32x32x16, R1-equivalent numerics ========
// QK^T: mfma(A=K, B=Q) -> P cols = q = lane&31 (softmax lane-local).
// PV:   mfma(A=V^T, B=P) -> O cols = q, rows = d.
// Exact running max (rescale gated on __any(pmax > m)); P <= 1; RNE f2bf packing.
__global__ __launch_bounds__(256) void attn2_k(const unsigned short* __restrict__ Q,
                                               const unsigned short* __restrict__ Kall,
                                               const unsigned short* __restrict__ VT,
                                               unsigned short* __restrict__ O) {
  __shared__ unsigned short ot[4][32][40];  // per-warp O-transpose epilogue scratch
  const int bid = blockIdx.x;
  const int swz = (bid & 7) * 64 + (bid >> 3);  // XCD-contiguous chunks
  const int qt = swz & 15, hk = (swz >> 4) & 7, b = swz >> 7;
  const int t = threadIdx.x, w = t >> 6, l = t & 63;
  const int q5 = l & 31, h = l >> 5;
  const bool lo_half = (h == 0);
  const float SCL2 = 0.12751879524622238f;  // 1/sqrt(128) * log2(e), applied in f32

  const int nq = qt * 32 + w * 8 + (q5 >> 2);
  const int g = q5 & 3;
  const int qpos = CACHE_C + nq;

  const unsigned short* Kb = Kall + (size_t)(b * 8 + hk) * TOTAL_C * 128;
  const unsigned short* Vb = VT + (size_t)(b * 8 + hk) * 128 * TOTAL_C;

  // Q fragments (B operand): col=q5, k = ks*16 + h*8 + j
  short8 qf[8];
  {
    const unsigned short* qrow =
        Q + (size_t)(b * 512 + nq) * 4096 + (hk * 4 + g) * 128 + h * 8;
#pragma unroll
    for (int ks = 0; ks < 8; ++ks) qf[ks] = *(const short8*)(qrow + ks * 16);
  }

  f32x16 oacc[4];
#pragma unroll
  for (int d = 0; d < 4; ++d)
#pragma unroll
    for (int r = 0; r < 16; ++r) oacc[d][r] = 0.f;
  float m = -1e30f, lsum = 0.f;

  const int nblk = ((CACHE_C + qt * 32 + w * 8 + 7) >> 6) + 1;

  for (int sb = 0; sb < nblk; ++sb) {
    const int s0 = sb << 6;
    // ---- QK^T (swapped): 16 MFMA ----
    f32x16 sa0, sa1;
#pragma unroll
    for (int r = 0; r < 16; ++r) { sa0[r] = 0.f; sa1[r] = 0.f; }
    const unsigned short* Krow0 = Kb + (size_t)(s0 + q5) * 128 + h * 8;
    const unsigned short* Krow1 = Krow0 + 32 * 128;
#pragma unroll
    for (int ks = 0; ks < 8; ++ks) {
      short8 k0 = *(const short8*)(Krow0 + ks * 16);
      short8 k1 = *(const short8*)(Krow1 + ks * 16);
      sa0 = __builtin_amdgcn_mfma_f32_32x32x16_bf16(k0, qf[ks], sa0, 0, 0, 0);
      sa1 = __builtin_amdgcn_mfma_f32_32x32x16_bf16(k1, qf[ks], sa1, 0, 0, 0);
    }
    // ---- scale in f32, then causal mask (only last block per warp) ----
#pragma unroll
    for (int r = 0; r < 16; ++r) { sa0[r] *= SCL2; sa1[r] *= SCL2; }
    if (sb == nblk - 1) {
#pragma unroll
      for (int r = 0; r < 16; ++r) {
        const int sg = s0 + ((r & 3) + 8 * (r >> 2) + 4 * h);
        if (sg > qpos) sa0[r] = -1e30f;
        if (sg + 32 > qpos) sa1[r] = -1e30f;
      }
    }
    // ---- row max (in-lane tree + cross-half) ----
    float m8[8];
#pragma unroll
    for (int i = 0; i < 8; ++i)
      m8[i] = fmaxf(fmaxf(sa0[i], sa0[i + 8]), fmaxf(sa1[i], sa1[i + 8]));
#pragma unroll
    for (int st = 4; st >= 1; st >>= 1)
#pragma unroll
      for (int i = 0; i < st; ++i) m8[i] = fmaxf(m8[i], m8[i + st]);
    const float pmax = fmaxf(m8[0], __shfl_xor(m8[0], 32));
    // ---- exact-max rescale (skip when max unchanged) ----
    if (__any(pmax > m)) {
      const float mn = fmaxf(m, pmax);
      const float sco = __builtin_amdgcn_exp2f(m - mn);
      m = mn;
      lsum *= sco;
#pragma unroll
      for (int d = 0; d < 4; ++d)
#pragma unroll
        for (int r = 0; r < 16; ++r) oacc[d][r] *= sco;
    }
    // ---- p = exp2(s - m) <= 1, pack to bf16 pairs (RNE) ----
    unsigned pk[16], sw[16];
    float s16[16];
#pragma unroll
    for (int i = 0; i < 8; ++i) {
      const float a0 = __builtin_amdgcn_exp2f(sa0[2 * i] - m);
      const float a1 = __builtin_amdgcn_exp2f(sa0[2 * i + 1] - m);
      const float b0 = __builtin_amdgcn_exp2f(sa1[2 * i] - m);
      const float b1 = __builtin_amdgcn_exp2f(sa1[2 * i + 1] - m);
      pk[i] = pack_bf16(a0, a1);
      pk[i + 8] = pack_bf16(b0, b1);
      s16[i] = a0 + a1;
      s16[i + 8] = b0 + b1;
    }
#pragma unroll
    for (int st = 8; st >= 1; st >>= 1)
#pragma unroll
      for (int i = 0; i < st; ++i) s16[i] += s16[i + st];
    lsum += s16[0];
    // ---- exchange halves, assemble P B-fragments, PV: 16 MFMA ----
#pragma unroll
    for (int i = 0; i < 16; ++i) sw[i] = __shfl_xor((int)pk[i], 32);
#pragma unroll
    for (int f = 0; f < 4; ++f) {
      union { int4 i4; short8 s8; } fr;
      fr.i4.x = lo_half ? pk[4 * f + 0] : sw[4 * f + 2];
      fr.i4.y = lo_half ? pk[4 * f + 1] : sw[4 * f + 3];
      fr.i4.z = lo_half ? sw[4 * f + 0] : pk[4 * f + 2];
      fr.i4.w = lo_half ? sw[4 * f + 1] : pk[4 * f + 3];
      const unsigned short* Vrow = Vb + (size_t)q5 * TOTAL_C + s0 + f * 16 + h * 8;
#pragma unroll
      for (int d = 0; d < 4; ++d) {
        short8 vf = *(const short8*)(Vrow + (size_t)d * 32 * TOTAL_C);
        oacc[d] = __builtin_amdgcn_mfma_f32_32x32x16_bf16(vf, fr.s8, oacc[d], 0, 0, 0);
      }
    }
  }

  // ---- epilogue: total lsum, divide, transpose via LDS, coalesced store ----
  lsum += __shfl_xor(lsum, 32);
  const float inv = 1.f / lsum;
#pragma unroll
  for (int db = 0; db < 4; ++db) {
    __syncthreads();  // anti-dep: previous iter's reads done before overwrite
#pragma unroll
    for (int r = 0; r < 16; r += 2) {
      const float v0 = oacc[db][r] * inv;
      const float v1 = oacc[db][r + 1] * inv;
      const int dloc = (r & 3) + 8 * (r >> 2) + 4 * h;
      *(unsigned*)&ot[w][q5][dloc] = pack_bf16(v0, v1);
    }
    __syncthreads();  // writes visible (and ordered) before reads
    const int qr_ = l >> 1, half = l & 1;
    const short8 ov0 = *(const short8*)&ot[w][qr_][half * 16];
    const short8 ov1 = *(const short8*)&ot[w][qr_][half * 16 + 8];
    const int n2 = qt * 32 + w * 8 + (qr_ >> 2), g2 = qr_ & 3;
    const size_t ob = (size_t)(b * 512 + n2) * 4096 + (hk * 4 + g2) * 128 + db * 32 + half * 16;
    *(short8*)&O[ob] = ov0;
    *(short8*)&O[ob + 8] = ov1;
  }
}

extern "C" void kernel_launch(void* const* d_in, const int* in_sizes, int n_in,
                              void* d_out, int out_size, void* d_ws, size_t ws_size,
                              hipStream_t stream) {
  const float* x = (const float*)d_in[0];
  const float* cosb = (const float*)d_in[1];
  const float* sinb = (const float*)d_in[2];
  const float* lnw = (const float*)d_in[3];
  const float* wq = (const float*)d_in[4];
  const float* wk = (const float*)d_in[5];
  const float* wv = (const float*)d_in[6];
  const float* wo = (const float*)d_in[7];
  const float* kcache = (const float*)d_in[8];
  const float* vcache = (const float*)d_in[9];
  float* out = (float*)d_out;
  char* ws = (char*)d_ws;

  unsigned short* hn    = (unsigned short*)(ws + 0);          // 16.8 MB
  unsigned short* wqkvT = (unsigned short*)(ws + 16777216);   // 50.3 MB
  unsigned short* qkv   = (unsigned short*)(ws + 67108864);   // 25.2 MB
  unsigned short* qrope = (unsigned short*)(ws + 92274688);   // 16.8 MB
  unsigned short* Kall  = (unsigned short*)(ws + 109051904);  // 37.75 MB
  unsigned short* VallT = (unsigned short*)(ws + 146800640);  // 37.75 MB
  unsigned short* attno = hn;     // alias: hn dead after QKV GEMM
  unsigned short* woT   = wqkvT;  // alias: wqkvT dead after QKV GEMM

  rmsnorm_k<<<2048, 256, 0, stream>>>(x, lnw, hn);
  build_wqkvT_k<<<dim3(192, 128), 256, 0, stream>>>(wq, wk, wv, wqkvT);
  gemm_bt<0><<<dim3(48, 16), 256, 0, stream>>>(hn, wqkvT, qkv, nullptr, nullptr, 2048, 6144, 4096);
  rope_k<<<2048, 256, 0, stream>>>(qkv, cosb, sinb, qrope, Kall);
  // new V (bf16, no rope): qkv[:,5120:6144] (2048x1024) -> VallT[...][CACHE+n]
  transpose_u16_k<<<dim3(32, 16, 4), 256, 0, stream>>>(qkv + 5120, 512L * QKV_N, QKV_N,
                                                       VallT + CACHE_C, 4718592L, TOTAL_C);
  // cached K: permute+convert
  cvt_kcache_k<<<16384, 256, 0, stream>>>(kcache, Kall);
  // cached V: transpose+convert  (z = b*8+h; src base = b*4718592 + h*128)
  transpose_cvt_k<<<dim3(4, 128, 32), 256, 0, stream>>>(vcache, 4718592L, 128L, 1024,
                                                        VallT, 589824L, TOTAL_C);
  attn2_k<<<512, 256, 0, stream>>>(qrope, Kall, VallT, attno);
  // woT bf16 (4096x4096) = wo^T
  transpose_cvt_k<<<dim3(128, 128, 1), 256, 0, stream>>>(wo, 0L, 0L, 4096, woT, 0L, 4096);
  gemm_bt<1><<<dim3(32, 16), 256, 0, stream>>>(attno, woT, nullptr, out, x, 2048, 4096, 4096);
}

// Round 5
// 562.136 us; speedup vs baseline: 1.5352x; 1.5352x over previous
//
#include <hip/hip_runtime.h>
#include <hip/hip_bf16.h>

typedef __attribute__((ext_vector_type(8))) short short8;
typedef __attribute__((ext_vector_type(4))) float floatx4;
typedef __attribute__((ext_vector_type(16))) float f32x16;

#define B_C 4
#define NEW_C 512
#define CACHE_C 4096
#define TOTAL_C 4608
#define H_C 32
#define HKV_C 8
#define D_C 128
#define HID_C 4096
#define QKV_N 6144

__device__ __forceinline__ unsigned short f2bf(float f) {
  union { float f; unsigned u; } v; v.f = f;
  unsigned r = v.u + 0x7FFFu + ((v.u >> 16) & 1u);
  return (unsigned short)(r >> 16);
}
__device__ __forceinline__ float bf2f(unsigned short h) {
  union { unsigned u; float f; } v; v.u = ((unsigned)h) << 16; return v.f;
}
__device__ __forceinline__ unsigned pack_bf16(float lo, float hi) {
  return ((unsigned)f2bf(hi) << 16) | (unsigned)f2bf(lo);
}
__device__ __forceinline__ void gload_lds16(const unsigned short* g, unsigned short* lds) {
  __builtin_amdgcn_global_load_lds(
      (const __attribute__((address_space(1))) unsigned int*)g,
      (__attribute__((address_space(3))) unsigned int*)lds, 16, 0, 0);
}

// ---------------- RMSNorm: x f32 (2048x4096) -> hn bf16 ----------------
__global__ __launch_bounds__(256) void rmsnorm_k(const float* __restrict__ x,
                                                 const float* __restrict__ g,
                                                 unsigned short* __restrict__ hn) {
  const int row = blockIdx.x;
  const int t = threadIdx.x;
  const float4* xr = (const float4*)(x + (size_t)row * 4096);
  float4 v[4];
  float ss = 0.f;
#pragma unroll
  for (int i = 0; i < 4; ++i) {
    v[i] = xr[t + i * 256];
    ss += v[i].x * v[i].x + v[i].y * v[i].y + v[i].z * v[i].z + v[i].w * v[i].w;
  }
#pragma unroll
  for (int m = 1; m < 64; m <<= 1) ss += __shfl_xor(ss, m);
  __shared__ float red[4];
  if ((t & 63) == 0) red[t >> 6] = ss;
  __syncthreads();
  ss = red[0] + red[1] + red[2] + red[3];
  const float inv = rsqrtf(ss * (1.f / 4096.f) + 1e-6f);
  const float4* gw = (const float4*)g;
#pragma unroll
  for (int i = 0; i < 4; ++i) {
    float4 w4 = gw[t + i * 256];
    ushort4 o;
    o.x = f2bf(v[i].x * inv * w4.x);
    o.y = f2bf(v[i].y * inv * w4.y);
    o.z = f2bf(v[i].z * inv * w4.z);
    o.w = f2bf(v[i].w * inv * w4.w);
    *(ushort4*)&hn[(size_t)row * 4096 + (t + i * 256) * 4] = o;
  }
}

// ---- build wqkvT bf16 (6144 x 4096): wqkvT[n][k] = {wq|wk|wv}[k][n] ----
__global__ __launch_bounds__(256) void build_wqkvT_k(const float* __restrict__ wq,
                                                     const float* __restrict__ wk,
                                                     const float* __restrict__ wv,
                                                     unsigned short* __restrict__ out) {
  __shared__ float tile[32][33];
  const int n0 = blockIdx.x * 32, k0 = blockIdx.y * 32;
  const float* src; int ld, nc;
  if (n0 < 4096)      { src = wq; ld = 4096; nc = n0; }
  else if (n0 < 5120) { src = wk; ld = 1024; nc = n0 - 4096; }
  else                { src = wv; ld = 1024; nc = n0 - 5120; }
  const int t = threadIdx.x, r = t >> 3, cv = (t & 7) * 4;
  const float4 v = *(const float4*)&src[(size_t)(k0 + r) * ld + nc + cv];
  tile[r][cv + 0] = v.x; tile[r][cv + 1] = v.y; tile[r][cv + 2] = v.z; tile[r][cv + 3] = v.w;
  __syncthreads();
  ushort4 o;
  o.x = f2bf(tile[cv + 0][r]); o.y = f2bf(tile[cv + 1][r]);
  o.z = f2bf(tile[cv + 2][r]); o.w = f2bf(tile[cv + 3][r]);
  *(ushort4*)&out[(size_t)(n0 + r) * 4096 + k0 + cv] = o;
}

// ---- generic f32->bf16 32x32 transpose: dst[c][r] = src[r][c] ----
__global__ __launch_bounds__(256) void transpose_cvt_k(const float* __restrict__ src,
                                                       long sbs_hi, long sbs_lo, int sld,
                                                       unsigned short* __restrict__ dst,
                                                       long dbs, int dld) {
  __shared__ float tile[32][33];
  const int z = blockIdx.z;
  const long sb = (long)(z >> 3) * sbs_hi + (long)(z & 7) * sbs_lo;
  const long db = (long)z * dbs;
  const int r0 = blockIdx.y * 32, c0 = blockIdx.x * 32;
  const int t = threadIdx.x, r = t >> 3, cv = (t & 7) * 4;
  const float4 v = *(const float4*)&src[sb + (long)(r0 + r) * sld + c0 + cv];
  tile[r][cv + 0] = v.x; tile[r][cv + 1] = v.y; tile[r][cv + 2] = v.z; tile[r][cv + 3] = v.w;
  __syncthreads();
  ushort4 o;
  o.x = f2bf(tile[cv + 0][r]); o.y = f2bf(tile[cv + 1][r]);
  o.z = f2bf(tile[cv + 2][r]); o.w = f2bf(tile[cv + 3][r]);
  *(ushort4*)&dst[db + (long)(c0 + r) * dld + r0 + cv] = o;
}

// ---- u16 32x32 transpose (no convert): dst[c][r] = src[r][c] ----
__global__ __launch_bounds__(256) void transpose_u16_k(const unsigned short* __restrict__ src,
                                                       long sbs, int sld,
                                                       unsigned short* __restrict__ dst,
                                                       long dbs, int dld) {
  __shared__ unsigned short tile[32][36];
  const int z = blockIdx.z;
  const long sb = (long)z * sbs;
  const long db = (long)z * dbs;
  const int r0 = blockIdx.y * 32, c0 = blockIdx.x * 32;
  const int t = threadIdx.x, r = t >> 3, cv = (t & 7) * 4;
  const ushort4 v = *(const ushort4*)&src[sb + (long)(r0 + r) * sld + c0 + cv];
  tile[r][cv + 0] = v.x; tile[r][cv + 1] = v.y; tile[r][cv + 2] = v.z; tile[r][cv + 3] = v.w;
  __syncthreads();
  ushort4 o;
  o.x = tile[cv + 0][r]; o.y = tile[cv + 1][r]; o.z = tile[cv + 2][r]; o.w = tile[cv + 3][r];
  *(ushort4*)&dst[db + (long)(c0 + r) * dld + r0 + cv] = o;
}

// ---- k_cache f32 (B,TOTAL,HKV,D) s<CACHE -> K_all bf16 (B,HKV,TOTAL,D) ----
__global__ __launch_bounds__(256) void cvt_kcache_k(const float* __restrict__ kc,
                                                    unsigned short* __restrict__ Kall) {
  const long i = (long)blockIdx.x * 256 + threadIdx.x;  // over 4*8*4096*32 float4
  const long c = i & 31, s = (i >> 5) & 4095, h = (i >> 17) & 7, b = i >> 20;
  const float4 v = *(const float4*)&kc[((b * 4608 + s) * 8 + h) * 128 + c * 4];
  ushort4 o;
  o.x = f2bf(v.x); o.y = f2bf(v.y); o.z = f2bf(v.z); o.w = f2bf(v.w);
  *(ushort4*)&Kall[((b * 8 + h) * 4608L + s) * 128 + c * 4] = o;
}

// ---- RoPE: qkv bf16 row -> q_rope bf16, K_all bf16 ----
__global__ __launch_bounds__(256) void rope_k(const unsigned short* __restrict__ qkv,
                                              const float* __restrict__ cosb,
                                              const float* __restrict__ sinb,
                                              unsigned short* __restrict__ qr,
                                              unsigned short* __restrict__ Kall) {
  const int row = blockIdx.x;
  const int b = row >> 9, n = row & 511;
  const unsigned short* src = qkv + (size_t)row * QKV_N;
  const float* cr = cosb + (size_t)row * 128;
  const float* sr = sinb + (size_t)row * 128;
  const int t = threadIdx.x;
#pragma unroll
  for (int i = 0; i < 8; ++i) {  // Q: 32 heads * 64 pairs
    int pid = t + i * 256;
    int hd = pid >> 6, d = pid & 63;
    int idx = hd * 128 + d;
    float a = bf2f(src[idx]), bb = bf2f(src[idx + 64]);
    float c0 = cr[d], s0 = sr[d], c1 = cr[d + 64], s1 = sr[d + 64];
    qr[(size_t)row * 4096 + idx] = f2bf(a * c0 - bb * s0);
    qr[(size_t)row * 4096 + idx + 64] = f2bf(bb * c1 + a * s1);
  }
#pragma unroll
  for (int i = 0; i < 2; ++i) {  // K: 8 heads * 64 pairs
    int pid = t + i * 256;
    int hd = pid >> 6, d = pid & 63;
    float a = bf2f(src[4096 + hd * 128 + d]), bb = bf2f(src[4096 + hd * 128 + d + 64]);
    float c0 = cr[d], s0 = sr[d], c1 = cr[d + 64], s1 = sr[d + 64];
    long kb = ((long)(b * 8 + hd) * TOTAL_C + CACHE_C + n) * 128 + d;
    Kall[kb] = f2bf(a * c0 - bb * s0);
    Kall[kb + 64] = f2bf(bb * c1 + a * s1);
  }
}

// ---------------- GEMM: C(MxN) = A(MxK) * BT(NxK)^T, bf16 MFMA ----------------
template <int EPI>
__global__ __launch_bounds__(256) void gemm_bt(const unsigned short* __restrict__ A,
                                               const unsigned short* __restrict__ BT,
                                               unsigned short* __restrict__ Cbf,
                                               float* __restrict__ Cf,
                                               const float* __restrict__ resid,
                                               int M, int N, int K) {
  __shared__ unsigned short As[128 * 32];
  __shared__ unsigned short Bs[128 * 32];
  const int n0 = blockIdx.x * 128, m0 = blockIdx.y * 128;
  const int t = threadIdx.x, w = t >> 6, l = t & 63;
  const int l15 = l & 15, lhi = l >> 4;
  const int wm = (w >> 1) * 64, wn = (w & 1) * 64;
  floatx4 acc[4][4];
#pragma unroll
  for (int mt = 0; mt < 4; ++mt)
#pragma unroll
    for (int nt = 0; nt < 4; ++nt)
#pragma unroll
      for (int r = 0; r < 4; ++r) acc[mt][nt][r] = 0.f;

  const int c0 = w * 2, c1 = w * 2 + 1;
  const unsigned short* ga0 = A + (size_t)(m0 + c0 * 16 + (l >> 2)) * K + (l & 3) * 8;
  const unsigned short* ga1 = A + (size_t)(m0 + c1 * 16 + (l >> 2)) * K + (l & 3) * 8;
  const unsigned short* gb0 = BT + (size_t)(n0 + c0 * 16 + (l >> 2)) * K + (l & 3) * 8;
  const unsigned short* gb1 = BT + (size_t)(n0 + c1 * 16 + (l >> 2)) * K + (l & 3) * 8;
  unsigned short* lA0 = &As[c0 * 512];
  unsigned short* lA1 = &As[c1 * 512];
  unsigned short* lB0 = &Bs[c0 * 512];
  unsigned short* lB1 = &Bs[c1 * 512];

  for (int k0 = 0; k0 < K; k0 += 32) {
    gload_lds16(ga0 + k0, lA0);
    gload_lds16(ga1 + k0, lA1);
    gload_lds16(gb0 + k0, lB0);
    gload_lds16(gb1 + k0, lB1);
    __syncthreads();
    short8 af[4], bfv[4];
#pragma unroll
    for (int i = 0; i < 4; ++i) {
      af[i] = *(const short8*)&As[(wm + i * 16 + l15) * 32 + lhi * 8];
      bfv[i] = *(const short8*)&Bs[(wn + i * 16 + l15) * 32 + lhi * 8];
    }
#pragma unroll
    for (int mt = 0; mt < 4; ++mt)
#pragma unroll
      for (int nt = 0; nt < 4; ++nt)
        acc[mt][nt] = __builtin_amdgcn_mfma_f32_16x16x32_bf16(af[mt], bfv[nt], acc[mt][nt], 0, 0, 0);
    __syncthreads();
  }
#pragma unroll
  for (int mt = 0; mt < 4; ++mt)
#pragma unroll
    for (int nt = 0; nt < 4; ++nt)
#pragma unroll
      for (int r = 0; r < 4; ++r) {
        const int row = m0 + wm + mt * 16 + lhi * 4 + r;
        const int col = n0 + wn + nt * 16 + l15;
        const size_t idx = (size_t)row * N + col;
        if (EPI == 0) Cbf[idx] = f2bf(acc[mt][nt][r]);
        else Cf[idx] = acc[mt][nt][r] + resid[idx];
      }
}

// ======== Flash attention v3: LDS-staged K/V (swizzled), dbuf, 1 barrier/iter ========
// Same math as v2b (R4, passing): swapped-operand 32x32x16, in-register softmax,
// exact running max, RNE packing. Only the K/V memory path changed.
__global__ __launch_bounds__(256, 2) void attn3_k(const unsigned short* __restrict__ Q,
                                                  const unsigned short* __restrict__ Kall,
                                                  const unsigned short* __restrict__ VT,
                                                  unsigned short* __restrict__ O) {
  __shared__ unsigned short Ks[2][8192];  // [64 s][128 d] per buf, XOR-swizzled 16B chunks
  __shared__ unsigned short Vs[2][8192];  // [128 d][64 s] per buf, XOR-swizzled 16B chunks
  __shared__ unsigned short ot[4][32][40];
  const int bid = blockIdx.x;
  const int swz = (bid & 7) * 64 + (bid >> 3);  // XCD-contiguous chunks
  const int qt = swz & 15, hk = (swz >> 4) & 7, b = swz >> 7;
  const int t = threadIdx.x, w = t >> 6, l = t & 63;
  const int q5 = l & 31, h = l >> 5;
  const bool lo_half = (h == 0);
  const float SCL2 = 0.12751879524622238f;  // 1/sqrt(128) * log2(e)

  const int nq = qt * 32 + w * 8 + (q5 >> 2);
  const int g = q5 & 3;
  const int qpos = CACHE_C + nq;

  const unsigned short* Kb = Kall + (size_t)(b * 8 + hk) * TOTAL_C * 128;
  const unsigned short* Vb = VT + (size_t)(b * 8 + hk) * 128 * TOTAL_C;

  // ---- staging: pre-swizzled global source, linear LDS dest (involution s) ----
  // K chunk c (16B): row=c>>4 (256B rows), s(c)=c^((c>>4)&7)
  // V chunk c (16B): row=c>>3 (128B rows), s(c)=c^((c>>3)&7)
  const unsigned short* ksrc[4];
  const unsigned short* vsrc[4];
#pragma unroll
  for (int j = 0; j < 4; ++j) {
    const int c = w * 256 + j * 64 + l;
    const int sck = c ^ ((c >> 4) & 7);
    ksrc[j] = Kb + sck * 8;                                    // +8192 elems / tile
    const int scv = c ^ ((c >> 3) & 7);
    vsrc[j] = Vb + (size_t)(c >> 3) * TOTAL_C + (scv & 7) * 8; // +64 elems / tile
  }

  // ---- swizzled LDS read base offsets (bytes, loop-invariant) ----
  const int xmask = (q5 & 7) << 4;
  int kb_[8], vb_[4];
#pragma unroll
  for (int ks = 0; ks < 8; ++ks) kb_[ks] = q5 * 256 + ((ks * 32 + h * 16) ^ xmask);
#pragma unroll
  for (int f = 0; f < 4; ++f) vb_[f] = q5 * 128 + ((f * 32 + h * 16) ^ xmask);

  // Q fragments (B operand): col=q5, k = ks*16 + h*8 + j
  short8 qf[8];
  {
    const unsigned short* qrow =
        Q + (size_t)(b * 512 + nq) * 4096 + (hk * 4 + g) * 128 + h * 8;
#pragma unroll
    for (int ks = 0; ks < 8; ++ks) qf[ks] = *(const short8*)(qrow + ks * 16);
  }

  f32x16 oacc[4];
#pragma unroll
  for (int d = 0; d < 4; ++d)
#pragma unroll
    for (int r = 0; r < 16; ++r) oacc[d][r] = 0.f;
  float m = -1e30f, lsum = 0.f;

  // block-uniform (all warps' causal boundaries fall in the same last 64-block)
  const int nblk = ((CACHE_C + qt * 32 + 31) >> 6) + 1;

  // prologue: stage tile 0
#pragma unroll
  for (int j = 0; j < 4; ++j) gload_lds16(ksrc[j], &Ks[0][w * 2048 + j * 512]);
#pragma unroll
  for (int j = 0; j < 4; ++j) gload_lds16(vsrc[j], &Vs[0][w * 2048 + j * 512]);

  for (int sb = 0; sb < nblk; ++sb) {
    __syncthreads();  // implicit vmcnt(0)+lgkmcnt(0): tile sb ready in buf[sb&1]
    if (sb + 1 < nblk) {
      const int p1 = (sb + 1) & 1;
#pragma unroll
      for (int j = 0; j < 4; ++j)
        gload_lds16(ksrc[j] + (sb + 1) * 8192, &Ks[p1][w * 2048 + j * 512]);
#pragma unroll
      for (int j = 0; j < 4; ++j)
        gload_lds16(vsrc[j] + (sb + 1) * 64, &Vs[p1][w * 2048 + j * 512]);
      __builtin_amdgcn_sched_barrier(0);  // keep prefetch issue early
    }
    const int s0 = sb << 6;
    const char* kp = (const char*)&Ks[sb & 1][0];
    const char* vp = (const char*)&Vs[sb & 1][0];

    // ---- QK^T (swapped): 16 MFMA from LDS ----
    f32x16 sa0, sa1;
#pragma unroll
    for (int r = 0; r < 16; ++r) { sa0[r] = 0.f; sa1[r] = 0.f; }
#pragma unroll
    for (int ks = 0; ks < 8; ++ks) {
      short8 k0 = *(const short8*)(kp + kb_[ks]);
      short8 k1 = *(const short8*)(kp + kb_[ks] + 8192);
      sa0 = __builtin_amdgcn_mfma_f32_32x32x16_bf16(k0, qf[ks], sa0, 0, 0, 0);
      sa1 = __builtin_amdgcn_mfma_f32_32x32x16_bf16(k1, qf[ks], sa1, 0, 0, 0);
    }
    // ---- scale in f32, then causal mask (only last block) ----
#pragma unroll
    for (int r = 0; r < 16; ++r) { sa0[r] *= SCL2; sa1[r] *= SCL2; }
    if (sb == nblk - 1) {
#pragma unroll
      for (int r = 0; r < 16; ++r) {
        const int sg = s0 + ((r & 3) + 8 * (r >> 2) + 4 * h);
        if (sg > qpos) sa0[r] = -1e30f;
        if (sg + 32 > qpos) sa1[r] = -1e30f;
      }
    }
    // ---- row max ----
    float m8[8];
#pragma unroll
    for (int i = 0; i < 8; ++i)
      m8[i] = fmaxf(fmaxf(sa0[i], sa0[i + 8]), fmaxf(sa1[i], sa1[i + 8]));
#pragma unroll
    for (int st = 4; st >= 1; st >>= 1)
#pragma unroll
      for (int i = 0; i < st; ++i) m8[i] = fmaxf(m8[i], m8[i + st]);
    const float pmax = fmaxf(m8[0], __shfl_xor(m8[0], 32));
    // ---- exact-max rescale (skip when max unchanged) ----
    if (__any(pmax > m)) {
      const float mn = fmaxf(m, pmax);
      const float sco = __builtin_amdgcn_exp2f(m - mn);
      m = mn;
      lsum *= sco;
#pragma unroll
      for (int d = 0; d < 4; ++d)
#pragma unroll
        for (int r = 0; r < 16; ++r) oacc[d][r] *= sco;
    }
    // ---- p = exp2(s - m) <= 1, RNE pack ----
    unsigned pk[16], sw[16];
    float s16[16];
#pragma unroll
    for (int i = 0; i < 8; ++i) {
      const float a0 = __builtin_amdgcn_exp2f(sa0[2 * i] - m);
      const float a1 = __builtin_amdgcn_exp2f(sa0[2 * i + 1] - m);
      const float b0 = __builtin_amdgcn_exp2f(sa1[2 * i] - m);
      const float b1 = __builtin_amdgcn_exp2f(sa1[2 * i + 1] - m);
      pk[i] = pack_bf16(a0, a1);
      pk[i + 8] = pack_bf16(b0, b1);
      s16[i] = a0 + a1;
      s16[i + 8] = b0 + b1;
    }
#pragma unroll
    for (int st = 8; st >= 1; st >>= 1)
#pragma unroll
      for (int i = 0; i < st; ++i) s16[i] += s16[i + st];
    lsum += s16[0];
    // ---- exchange halves, assemble P, PV: 16 MFMA from LDS ----
#pragma unroll
    for (int i = 0; i < 16; ++i) sw[i] = __shfl_xor((int)pk[i], 32);
#pragma unroll
    for (int f = 0; f < 4; ++f) {
      union { int4 i4; short8 s8; } fr;
      fr.i4.x = lo_half ? pk[4 * f + 0] : sw[4 * f + 2];
      fr.i4.y = lo_half ? pk[4 * f + 1] : sw[4 * f + 3];
      fr.i4.z = lo_half ? sw[4 * f + 0] : pk[4 * f + 2];
      fr.i4.w = lo_half ? sw[4 * f + 1] : pk[4 * f + 3];
#pragma unroll
      for (int d = 0; d < 4; ++d) {
        short8 vf = *(const short8*)(vp + vb_[f] + d * 4096);
        oacc[d] = __builtin_amdgcn_mfma_f32_32x32x16_bf16(vf, fr.s8, oacc[d], 0, 0, 0);
      }
    }
  }

  // ---- epilogue: total lsum, divide, transpose via LDS, coalesced store ----
  lsum += __shfl_xor(lsum, 32);
  const float inv = 1.f / lsum;
#pragma unroll
  for (int db = 0; db < 4; ++db) {
    __syncthreads();
#pragma unroll
    for (int r = 0; r < 16; r += 2) {
      const float v0 = oacc[db][r] * inv;
      const float v1 = oacc[db][r + 1] * inv;
      const int dloc = (r & 3) + 8 * (r >> 2) + 4 * h;
      *(unsigned*)&ot[w][q5][dloc] = pack_bf16(v0, v1);
    }
    __syncthreads();
    const int qr_ = l >> 1, half = l & 1;
    const short8 ov0 = *(const short8*)&ot[w][qr_][half * 16];
    const short8 ov1 = *(const short8*)&ot[w][qr_][half * 16 + 8];
    const int n2 = qt * 32 + w * 8 + (qr_ >> 2), g2 = qr_ & 3;
    const size_t ob = (size_t)(b * 512 + n2) * 4096 + (hk * 4 + g2) * 128 + db * 32 + half * 16;
    *(short8*)&O[ob] = ov0;
    *(short8*)&O[ob + 8] = ov1;
  }
}

extern "C" void kernel_launch(void* const* d_in, const int* in_sizes, int n_in,
                              void* d_out, int out_size, void* d_ws, size_t ws_size,
                              hipStream_t stream) {
  const float* x = (const float*)d_in[0];
  const float* cosb = (const float*)d_in[1];
  const float* sinb = (const float*)d_in[2];
  const float* lnw = (const float*)d_in[3];
  const float* wq = (const float*)d_in[4];
  const float* wk = (const float*)d_in[5];
  const float* wv = (const float*)d_in[6];
  const float* wo = (const float*)d_in[7];
  const float* kcache = (const float*)d_in[8];
  const float* vcache = (const float*)d_in[9];
  float* out = (float*)d_out;
  char* ws = (char*)d_ws;

  unsigned short* hn    = (unsigned short*)(ws + 0);          // 16.8 MB
  unsigned short* wqkvT = (unsigned short*)(ws + 16777216);   // 50.3 MB
  unsigned short* qkv   = (unsigned short*)(ws + 67108864);   // 25.2 MB
  unsigned short* qrope = (unsigned short*)(ws + 92274688);   // 16.8 MB
  unsigned short* Kall  = (unsigned short*)(ws + 109051904);  // 37.75 MB
  unsigned short* VallT = (unsigned short*)(ws + 146800640);  // 37.75 MB
  unsigned short* attno = hn;     // alias: hn dead after QKV GEMM
  unsigned short* woT   = wqkvT;  // alias: wqkvT dead after QKV GEMM

  rmsnorm_k<<<2048, 256, 0, stream>>>(x, lnw, hn);
  build_wqkvT_k<<<dim3(192, 128), 256, 0, stream>>>(wq, wk, wv, wqkvT);
  gemm_bt<0><<<dim3(48, 16), 256, 0, stream>>>(hn, wqkvT, qkv, nullptr, nullptr, 2048, 6144, 4096);
  rope_k<<<2048, 256, 0, stream>>>(qkv, cosb, sinb, qrope, Kall);
  // new V (bf16, no rope): qkv[:,5120:6144] (2048x1024) -> VallT[...][CACHE+n]
  transpose_u16_k<<<dim3(32, 16, 4), 256, 0, stream>>>(qkv + 5120, 512L * QKV_N, QKV_N,
                                                       VallT + CACHE_C, 4718592L, TOTAL_C);
  // cached K: permute+convert
  cvt_kcache_k<<<16384, 256, 0, stream>>>(kcache, Kall);
  // cached V: transpose+convert  (z = b*8+h; src base = b*4718592 + h*128)
  transpose_cvt_k<<<dim3(4, 128, 32), 256, 0, stream>>>(vcache, 4718592L, 128L, 1024,
                                                        VallT, 589824L, TOTAL_C);
  attn3_k<<<512, 256, 0, stream>>>(qrope, Kall, VallT, attno);
  // woT bf16 (4096x4096) = wo^T
  transpose_cvt_k<<<dim3(128, 128, 1), 256, 0, stream>>>(wo, 0L, 0L, 4096, woT, 0L, 4096);
  gemm_bt<1><<<dim3(32, 16), 256, 0, stream>>>(attno, woT, nullptr, out, x, 2048, 4096, 4096);
}

// Round 7
// 542.997 us; speedup vs baseline: 1.5893x; 1.0352x over previous
//
#include <hip/hip_runtime.h>
#include <hip/hip_bf16.h>

typedef __attribute__((ext_vector_type(8))) short short8;
typedef __attribute__((ext_vector_type(4))) float floatx4;
typedef __attribute__((ext_vector_type(16))) float f32x16;

#define B_C 4
#define NEW_C 512
#define CACHE_C 4096
#define TOTAL_C 4608
#define H_C 32
#define HKV_C 8
#define D_C 128
#define HID_C 4096
#define QKV_N 6144

__device__ __forceinline__ unsigned short f2bf(float f) {
  union { float f; unsigned u; } v; v.f = f;
  unsigned r = v.u + 0x7FFFu + ((v.u >> 16) & 1u);
  return (unsigned short)(r >> 16);
}
__device__ __forceinline__ float bf2f(unsigned short h) {
  union { unsigned u; float f; } v; v.u = ((unsigned)h) << 16; return v.f;
}
__device__ __forceinline__ unsigned pack_bf16(float lo, float hi) {
  return ((unsigned)f2bf(hi) << 16) | (unsigned)f2bf(lo);
}
// single v_perm_b32: D = {hi.b3, hi.b2, lo.b3, lo.b2} — bf16 pair via truncation (RTZ).
__device__ __forceinline__ unsigned pack_trunc(float lo, float hi) {
  union { float f; unsigned u; } a, b;
  a.f = lo; b.f = hi;
  return __builtin_amdgcn_perm(b.u, a.u, 0x07060302u);
}
__device__ __forceinline__ void gload_lds16(const unsigned short* g, unsigned short* lds) {
  __builtin_amdgcn_global_load_lds(
      (const __attribute__((address_space(1))) unsigned int*)g,
      (__attribute__((address_space(3))) unsigned int*)lds, 16, 0, 0);
}

// ---------------- RMSNorm: x f32 (2048x4096) -> hn bf16 ----------------
__global__ __launch_bounds__(256) void rmsnorm_k(const float* __restrict__ x,
                                                 const float* __restrict__ g,
                                                 unsigned short* __restrict__ hn) {
  const int row = blockIdx.x;
  const int t = threadIdx.x;
  const float4* xr = (const float4*)(x + (size_t)row * 4096);
  float4 v[4];
  float ss = 0.f;
#pragma unroll
  for (int i = 0; i < 4; ++i) {
    v[i] = xr[t + i * 256];
    ss += v[i].x * v[i].x + v[i].y * v[i].y + v[i].z * v[i].z + v[i].w * v[i].w;
  }
#pragma unroll
  for (int m = 1; m < 64; m <<= 1) ss += __shfl_xor(ss, m);
  __shared__ float red[4];
  if ((t & 63) == 0) red[t >> 6] = ss;
  __syncthreads();
  ss = red[0] + red[1] + red[2] + red[3];
  const float inv = rsqrtf(ss * (1.f / 4096.f) + 1e-6f);
  const float4* gw = (const float4*)g;
#pragma unroll
  for (int i = 0; i < 4; ++i) {
    float4 w4 = gw[t + i * 256];
    ushort4 o;
    o.x = f2bf(v[i].x * inv * w4.x);
    o.y = f2bf(v[i].y * inv * w4.y);
    o.z = f2bf(v[i].z * inv * w4.z);
    o.w = f2bf(v[i].w * inv * w4.w);
    *(ushort4*)&hn[(size_t)row * 4096 + (t + i * 256) * 4] = o;
  }
}

// ---- build wqkvT bf16 (6144 x 4096): wqkvT[n][k] = {wq|wk|wv}[k][n] ----
__global__ __launch_bounds__(256) void build_wqkvT_k(const float* __restrict__ wq,
                                                     const float* __restrict__ wk,
                                                     const float* __restrict__ wv,
                                                     unsigned short* __restrict__ out) {
  __shared__ float tile[32][33];
  const int n0 = blockIdx.x * 32, k0 = blockIdx.y * 32;
  const float* src; int ld, nc;
  if (n0 < 4096)      { src = wq; ld = 4096; nc = n0; }
  else if (n0 < 5120) { src = wk; ld = 1024; nc = n0 - 4096; }
  else                { src = wv; ld = 1024; nc = n0 - 5120; }
  const int t = threadIdx.x, r = t >> 3, cv = (t & 7) * 4;
  const float4 v = *(const float4*)&src[(size_t)(k0 + r) * ld + nc + cv];
  tile[r][cv + 0] = v.x; tile[r][cv + 1] = v.y; tile[r][cv + 2] = v.z; tile[r][cv + 3] = v.w;
  __syncthreads();
  ushort4 o;
  o.x = f2bf(tile[cv + 0][r]); o.y = f2bf(tile[cv + 1][r]);
  o.z = f2bf(tile[cv + 2][r]); o.w = f2bf(tile[cv + 3][r]);
  *(ushort4*)&out[(size_t)(n0 + r) * 4096 + k0 + cv] = o;
}

// ---- generic f32->bf16 32x32 transpose: dst[c][r] = src[r][c] ----
__global__ __launch_bounds__(256) void transpose_cvt_k(const float* __restrict__ src,
                                                       long sbs_hi, long sbs_lo, int sld,
                                                       unsigned short* __restrict__ dst,
                                                       long dbs, int dld) {
  __shared__ float tile[32][33];
  const int z = blockIdx.z;
  const long sb = (long)(z >> 3) * sbs_hi + (long)(z & 7) * sbs_lo;
  const long db = (long)z * dbs;
  const int r0 = blockIdx.y * 32, c0 = blockIdx.x * 32;
  const int t = threadIdx.x, r = t >> 3, cv = (t & 7) * 4;
  const float4 v = *(const float4*)&src[sb + (long)(r0 + r) * sld + c0 + cv];
  tile[r][cv + 0] = v.x; tile[r][cv + 1] = v.y; tile[r][cv + 2] = v.z; tile[r][cv + 3] = v.w;
  __syncthreads();
  ushort4 o;
  o.x = f2bf(tile[cv + 0][r]); o.y = f2bf(tile[cv + 1][r]);
  o.z = f2bf(tile[cv + 2][r]); o.w = f2bf(tile[cv + 3][r]);
  *(ushort4*)&dst[db + (long)(c0 + r) * dld + r0 + cv] = o;
}

// ---- u16 32x32 transpose (no convert): dst[c][r] = src[r][c] ----
__global__ __launch_bounds__(256) void transpose_u16_k(const unsigned short* __restrict__ src,
                                                       long sbs, int sld,
                                                       unsigned short* __restrict__ dst,
                                                       long dbs, int dld) {
  __shared__ unsigned short tile[32][36];
  const int z = blockIdx.z;
  const long sb = (long)z * sbs;
  const long db = (long)z * dbs;
  const int r0 = blockIdx.y * 32, c0 = blockIdx.x * 32;
  const int t = threadIdx.x, r = t >> 3, cv = (t & 7) * 4;
  const ushort4 v = *(const ushort4*)&src[sb + (long)(r0 + r) * sld + c0 + cv];
  tile[r][cv + 0] = v.x; tile[r][cv + 1] = v.y; tile[r][cv + 2] = v.z; tile[r][cv + 3] = v.w;
  __syncthreads();
  ushort4 o;
  o.x = tile[cv + 0][r]; o.y = tile[cv + 1][r]; o.z = tile[cv + 2][r]; o.w = tile[cv + 3][r];
  *(ushort4*)&dst[db + (long)(c0 + r) * dld + r0 + cv] = o;
}

// ---- k_cache f32 (B,TOTAL,HKV,D) s<CACHE -> K_all bf16 (B,HKV,TOTAL,D) ----
__global__ __launch_bounds__(256) void cvt_kcache_k(const float* __restrict__ kc,
                                                    unsigned short* __restrict__ Kall) {
  const long i = (long)blockIdx.x * 256 + threadIdx.x;  // over 4*8*4096*32 float4
  const long c = i & 31, s = (i >> 5) & 4095, h = (i >> 17) & 7, b = i >> 20;
  const float4 v = *(const float4*)&kc[((b * 4608 + s) * 8 + h) * 128 + c * 4];
  ushort4 o;
  o.x = f2bf(v.x); o.y = f2bf(v.y); o.z = f2bf(v.z); o.w = f2bf(v.w);
  *(ushort4*)&Kall[((b * 8 + h) * 4608L + s) * 128 + c * 4] = o;
}

// ---- RoPE: qkv bf16 row -> q_rope bf16 (PRE-SCALED by 1/sqrt(D)*log2e), K_all bf16 ----
__global__ __launch_bounds__(256) void rope_k(const unsigned short* __restrict__ qkv,
                                              const float* __restrict__ cosb,
                                              const float* __restrict__ sinb,
                                              unsigned short* __restrict__ qr,
                                              unsigned short* __restrict__ Kall) {
  const float SCL = 0.08838834764831845f * 1.4426950408889634f;  // 1/sqrt(128) * log2(e)
  const int row = blockIdx.x;
  const int b = row >> 9, n = row & 511;
  const unsigned short* src = qkv + (size_t)row * QKV_N;
  const float* cr = cosb + (size_t)row * 128;
  const float* sr = sinb + (size_t)row * 128;
  const int t = threadIdx.x;
#pragma unroll
  for (int i = 0; i < 8; ++i) {  // Q: 32 heads * 64 pairs
    int pid = t + i * 256;
    int hd = pid >> 6, d = pid & 63;
    int idx = hd * 128 + d;
    float a = bf2f(src[idx]), bb = bf2f(src[idx + 64]);
    float c0 = cr[d], s0 = sr[d], c1 = cr[d + 64], s1 = sr[d + 64];
    qr[(size_t)row * 4096 + idx] = f2bf((a * c0 - bb * s0) * SCL);
    qr[(size_t)row * 4096 + idx + 64] = f2bf((bb * c1 + a * s1) * SCL);
  }
#pragma unroll
  for (int i = 0; i < 2; ++i) {  // K: 8 heads * 64 pairs
    int pid = t + i * 256;
    int hd = pid >> 6, d = pid & 63;
    float a = bf2f(src[4096 + hd * 128 + d]), bb = bf2f(src[4096 + hd * 128 + d + 64]);
    float c0 = cr[d], s0 = sr[d], c1 = cr[d + 64], s1 = sr[d + 64];
    long kb = ((long)(b * 8 + hd) * TOTAL_C + CACHE_C + n) * 128 + d;
    Kall[kb] = f2bf(a * c0 - bb * s0);
    Kall[kb + 64] = f2bf(bb * c1 + a * s1);
  }
}

// ---------------- GEMM: C(MxN) = A(MxK) * BT(NxK)^T, bf16 MFMA ----------------
template <int EPI>
__global__ __launch_bounds__(256) void gemm_bt(const unsigned short* __restrict__ A,
                                               const unsigned short* __restrict__ BT,
                                               unsigned short* __restrict__ Cbf,
                                               float* __restrict__ Cf,
                                               const float* __restrict__ resid,
                                               int M, int N, int K) {
  __shared__ unsigned short As[128 * 32];
  __shared__ unsigned short Bs[128 * 32];
  const int n0 = blockIdx.x * 128, m0 = blockIdx.y * 128;
  const int t = threadIdx.x, w = t >> 6, l = t & 63;
  const int l15 = l & 15, lhi = l >> 4;
  const int wm = (w >> 1) * 64, wn = (w & 1) * 64;
  floatx4 acc[4][4];
#pragma unroll
  for (int mt = 0; mt < 4; ++mt)
#pragma unroll
    for (int nt = 0; nt < 4; ++nt)
#pragma unroll
      for (int r = 0; r < 4; ++r) acc[mt][nt][r] = 0.f;

  const int c0 = w * 2, c1 = w * 2 + 1;
  const unsigned short* ga0 = A + (size_t)(m0 + c0 * 16 + (l >> 2)) * K + (l & 3) * 8;
  const unsigned short* ga1 = A + (size_t)(m0 + c1 * 16 + (l >> 2)) * K + (l & 3) * 8;
  const unsigned short* gb0 = BT + (size_t)(n0 + c0 * 16 + (l >> 2)) * K + (l & 3) * 8;
  const unsigned short* gb1 = BT + (size_t)(n0 + c1 * 16 + (l >> 2)) * K + (l & 3) * 8;
  unsigned short* lA0 = &As[c0 * 512];
  unsigned short* lA1 = &As[c1 * 512];
  unsigned short* lB0 = &Bs[c0 * 512];
  unsigned short* lB1 = &Bs[c1 * 512];

  for (int k0 = 0; k0 < K; k0 += 32) {
    gload_lds16(ga0 + k0, lA0);
    gload_lds16(ga1 + k0, lA1);
    gload_lds16(gb0 + k0, lB0);
    gload_lds16(gb1 + k0, lB1);
    __syncthreads();
    short8 af[4], bfv[4];
#pragma unroll
    for (int i = 0; i < 4; ++i) {
      af[i] = *(const short8*)&As[(wm + i * 16 + l15) * 32 + lhi * 8];
      bfv[i] = *(const short8*)&Bs[(wn + i * 16 + l15) * 32 + lhi * 8];
    }
#pragma unroll
    for (int mt = 0; mt < 4; ++mt)
#pragma unroll
      for (int nt = 0; nt < 4; ++nt)
        acc[mt][nt] = __builtin_amdgcn_mfma_f32_16x16x32_bf16(af[mt], bfv[nt], acc[mt][nt], 0, 0, 0);
    __syncthreads();
  }
#pragma unroll
  for (int mt = 0; mt < 4; ++mt)
#pragma unroll
    for (int nt = 0; nt < 4; ++nt)
#pragma unroll
      for (int r = 0; r < 4; ++r) {
        const int row = m0 + wm + mt * 16 + lhi * 4 + r;
        const int col = n0 + wn + nt * 16 + l15;
        const size_t idx = (size_t)row * N + col;
        if (EPI == 0) Cbf[idx] = f2bf(acc[mt][nt][r]);
        else Cf[idx] = acc[mt][nt][r] + resid[idx];
      }
}

// ======== Flash attention v5: R5 memory path + prescaled Q + v_perm pack ========
// Swapped-operand 32x32x16, in-register softmax, exact running max.
// Q pre-scaled by 1/sqrt(D)*log2e in rope_k; P packed via single v_perm_b32 (RTZ).
__global__ __launch_bounds__(256, 2) void attn3_k(const unsigned short* __restrict__ Q,
                                                  const unsigned short* __restrict__ Kall,
                                                  const unsigned short* __restrict__ VT,
                                                  unsigned short* __restrict__ O) {
  __shared__ unsigned short Ks[2][8192];  // [64 s][128 d] per buf, XOR-swizzled 16B chunks
  __shared__ unsigned short Vs[2][8192];  // [128 d][64 s] per buf, XOR-swizzled 16B chunks
  __shared__ unsigned short ot[4][32][40];
  const int bid = blockIdx.x;
  const int swz = (bid & 7) * 64 + (bid >> 3);  // XCD-contiguous chunks
  const int qt = swz & 15, hk = (swz >> 4) & 7, b = swz >> 7;
  const int t = threadIdx.x, w = t >> 6, l = t & 63;
  const int q5 = l & 31, h = l >> 5;
  const bool lo_half = (h == 0);

  const int nq = qt * 32 + w * 8 + (q5 >> 2);
  const int g = q5 & 3;
  const int qpos = CACHE_C + nq;

  const unsigned short* Kb = Kall + (size_t)(b * 8 + hk) * TOTAL_C * 128;
  const unsigned short* Vb = VT + (size_t)(b * 8 + hk) * 128 * TOTAL_C;

  // ---- staging: pre-swizzled global source, linear LDS dest (involution s) ----
  const unsigned short* ksrc[4];
  const unsigned short* vsrc[4];
#pragma unroll
  for (int j = 0; j < 4; ++j) {
    const int c = w * 256 + j * 64 + l;
    const int sck = c ^ ((c >> 4) & 7);
    ksrc[j] = Kb + sck * 8;                                    // +8192 elems / tile
    const int scv = c ^ ((c >> 3) & 7);
    vsrc[j] = Vb + (size_t)(c >> 3) * TOTAL_C + (scv & 7) * 8; // +64 elems / tile
  }

  // ---- swizzled LDS read base offsets (bytes, loop-invariant) ----
  const int xmask = (q5 & 7) << 4;
  int kb_[8], vb_[4];
#pragma unroll
  for (int ks = 0; ks < 8; ++ks) kb_[ks] = q5 * 256 + ((ks * 32 + h * 16) ^ xmask);
#pragma unroll
  for (int f = 0; f < 4; ++f) vb_[f] = q5 * 128 + ((f * 32 + h * 16) ^ xmask);

  // Q fragments (B operand): col=q5, k = ks*16 + h*8 + j
  short8 qf[8];
  {
    const unsigned short* qrow =
        Q + (size_t)(b * 512 + nq) * 4096 + (hk * 4 + g) * 128 + h * 8;
#pragma unroll
    for (int ks = 0; ks < 8; ++ks) qf[ks] = *(const short8*)(qrow + ks * 16);
  }

  f32x16 oacc[4];
#pragma unroll
  for (int d = 0; d < 4; ++d)
#pragma unroll
    for (int r = 0; r < 16; ++r) oacc[d][r] = 0.f;
  float m = -1e30f, lsum = 0.f;

  // block-uniform (all warps' causal boundaries fall in the same last 64-block)
  const int nblk = ((CACHE_C + qt * 32 + 31) >> 6) + 1;

  // prologue: stage tile 0
#pragma unroll
  for (int j = 0; j < 4; ++j) gload_lds16(ksrc[j], &Ks[0][w * 2048 + j * 512]);
#pragma unroll
  for (int j = 0; j < 4; ++j) gload_lds16(vsrc[j], &Vs[0][w * 2048 + j * 512]);

  for (int sb = 0; sb < nblk; ++sb) {
    __syncthreads();  // implicit vmcnt(0)+lgkmcnt(0): tile sb ready in buf[sb&1]
    if (sb + 1 < nblk) {
      const int p1 = (sb + 1) & 1;
#pragma unroll
      for (int j = 0; j < 4; ++j)
        gload_lds16(ksrc[j] + (sb + 1) * 8192, &Ks[p1][w * 2048 + j * 512]);
#pragma unroll
      for (int j = 0; j < 4; ++j)
        gload_lds16(vsrc[j] + (sb + 1) * 64, &Vs[p1][w * 2048 + j * 512]);
      __builtin_amdgcn_sched_barrier(0);  // keep prefetch issue early
    }
    const int s0 = sb << 6;
    const char* kp = (const char*)&Ks[sb & 1][0];
    const char* vp = (const char*)&Vs[sb & 1][0];

    // ---- QK^T (swapped): 16 MFMA from LDS; scores already in log2 units ----
    f32x16 sa0, sa1;
#pragma unroll
    for (int r = 0; r < 16; ++r) { sa0[r] = 0.f; sa1[r] = 0.f; }
#pragma unroll
    for (int ks = 0; ks < 8; ++ks) {
      short8 k0 = *(const short8*)(kp + kb_[ks]);
      short8 k1 = *(const short8*)(kp + kb_[ks] + 8192);
      sa0 = __builtin_amdgcn_mfma_f32_32x32x16_bf16(k0, qf[ks], sa0, 0, 0, 0);
      sa1 = __builtin_amdgcn_mfma_f32_32x32x16_bf16(k1, qf[ks], sa1, 0, 0, 0);
    }
    // ---- causal mask (only last block) ----
    if (sb == nblk - 1) {
#pragma unroll
      for (int r = 0; r < 16; ++r) {
        const int sg = s0 + ((r & 3) + 8 * (r >> 2) + 4 * h);
        if (sg > qpos) sa0[r] = -1e30f;
        if (sg + 32 > qpos) sa1[r] = -1e30f;
      }
    }
    // ---- row max ----
    float m8[8];
#pragma unroll
    for (int i = 0; i < 8; ++i)
      m8[i] = fmaxf(fmaxf(sa0[i], sa0[i + 8]), fmaxf(sa1[i], sa1[i + 8]));
#pragma unroll
    for (int st = 4; st >= 1; st >>= 1)
#pragma unroll
      for (int i = 0; i < st; ++i) m8[i] = fmaxf(m8[i], m8[i + st]);
    const float pmax = fmaxf(m8[0], __shfl_xor(m8[0], 32));
    // ---- exact-max rescale (skip when max unchanged) ----
    if (__any(pmax > m)) {
      const float mn = fmaxf(m, pmax);
      const float sco = __builtin_amdgcn_exp2f(m - mn);
      m = mn;
      lsum *= sco;
#pragma unroll
      for (int d = 0; d < 4; ++d)
#pragma unroll
        for (int r = 0; r < 16; ++r) oacc[d][r] *= sco;
    }
    // ---- p = exp2(s - m) <= 1, pack via v_perm_b32 (RTZ) ----
    unsigned pk[16], sw[16];
    float s16[16];
#pragma unroll
    for (int i = 0; i < 8; ++i) {
      const float a0 = __builtin_amdgcn_exp2f(sa0[2 * i] - m);
      const float a1 = __builtin_amdgcn_exp2f(sa0[2 * i + 1] - m);
      const float b0 = __builtin_amdgcn_exp2f(sa1[2 * i] - m);
      const float b1 = __builtin_amdgcn_exp2f(sa1[2 * i + 1] - m);
      pk[i] = pack_trunc(a0, a1);
      pk[i + 8] = pack_trunc(b0, b1);
      s16[i] = a0 + a1;
      s16[i + 8] = b0 + b1;
    }
#pragma unroll
    for (int st = 8; st >= 1; st >>= 1)
#pragma unroll
      for (int i = 0; i < st; ++i) s16[i] += s16[i + st];
    lsum += s16[0];
    // ---- exchange halves, assemble P, PV: 16 MFMA from LDS ----
#pragma unroll
    for (int i = 0; i < 16; ++i) sw[i] = __shfl_xor((int)pk[i], 32);
#pragma unroll
    for (int f = 0; f < 4; ++f) {
      union { int4 i4; short8 s8; } fr;
      fr.i4.x = lo_half ? pk[4 * f + 0] : sw[4 * f + 2];
      fr.i4.y = lo_half ? pk[4 * f + 1] : sw[4 * f + 3];
      fr.i4.z = lo_half ? sw[4 * f + 0] : pk[4 * f + 2];
      fr.i4.w = lo_half ? sw[4 * f + 1] : pk[4 * f + 3];
#pragma unroll
      for (int d = 0; d < 4; ++d) {
        short8 vf = *(const short8*)(vp + vb_[f] + d * 4096);
        oacc[d] = __builtin_amdgcn_mfma_f32_32x32x16_bf16(vf, fr.s8, oacc[d], 0, 0, 0);
      }
    }
  }

  // ---- epilogue: total lsum, divide, transpose via LDS, coalesced store ----
  lsum += __shfl_xor(lsum, 32);
  const float inv = 1.f / lsum;
#pragma unroll
  for (int db = 0; db < 4; ++db) {
    __syncthreads();
#pragma unroll
    for (int r = 0; r < 16; r += 2) {
      const float v0 = oacc[db][r] * inv;
      const float v1 = oacc[db][r + 1] * inv;
      const int dloc = (r & 3) + 8 * (r >> 2) + 4 * h;
      *(unsigned*)&ot[w][q5][dloc] = pack_bf16(v0, v1);
    }
    __syncthreads();
    const int qr_ = l >> 1, half = l & 1;
    const short8 ov0 = *(const short8*)&ot[w][qr_][half * 16];
    const short8 ov1 = *(const short8*)&ot[w][qr_][half * 16 + 8];
    const int n2 = qt * 32 + w * 8 + (qr_ >> 2), g2 = qr_ & 3;
    const size_t ob = (size_t)(b * 512 + n2) * 4096 + (hk * 4 + g2) * 128 + db * 32 + half * 16;
    *(short8*)&O[ob] = ov0;
    *(short8*)&O[ob + 8] = ov1;
  }
}

extern "C" void kernel_launch(void* const* d_in, const int* in_sizes, int n_in,
                              void* d_out, int out_size, void* d_ws, size_t ws_size,
                              hipStream_t stream) {
  const float* x = (const float*)d_in[0];
  const float* cosb = (const float*)d_in[1];
  const float* sinb = (const float*)d_in[2];
  const float* lnw = (const float*)d_in[3];
  const float* wq = (const float*)d_in[4];
  const float* wk = (const float*)d_in[5];
  const float* wv = (const float*)d_in[6];
  const float* wo = (const float*)d_in[7];
  const float* kcache = (const float*)d_in[8];
  const float* vcache = (const float*)d_in[9];
  float* out = (float*)d_out;
  char* ws = (char*)d_ws;

  unsigned short* hn    = (unsigned short*)(ws + 0);          // 16.8 MB
  unsigned short* wqkvT = (unsigned short*)(ws + 16777216);   // 50.3 MB
  unsigned short* qkv   = (unsigned short*)(ws + 67108864);   // 25.2 MB
  unsigned short* qrope = (unsigned short*)(ws + 92274688);   // 16.8 MB
  unsigned short* Kall  = (unsigned short*)(ws + 109051904);  // 37.75 MB
  unsigned short* VallT = (unsigned short*)(ws + 146800640);  // 37.75 MB
  unsigned short* attno = hn;     // alias: hn dead after QKV GEMM
  unsigned short* woT   = wqkvT;  // alias: wqkvT dead after QKV GEMM

  rmsnorm_k<<<2048, 256, 0, stream>>>(x, lnw, hn);
  build_wqkvT_k<<<dim3(192, 128), 256, 0, stream>>>(wq, wk, wv, wqkvT);
  gemm_bt<0><<<dim3(48, 16), 256, 0, stream>>>(hn, wqkvT, qkv, nullptr, nullptr, 2048, 6144, 4096);
  rope_k<<<2048, 256, 0, stream>>>(qkv, cosb, sinb, qrope, Kall);
  // new V (bf16, no rope): qkv[:,5120:6144] (2048x1024) -> VallT[...][CACHE+n]
  transpose_u16_k<<<dim3(32, 16, 4), 256, 0, stream>>>(qkv + 5120, 512L * QKV_N, QKV_N,
                                                       VallT + CACHE_C, 4718592L, TOTAL_C);
  // cached K: permute+convert
  cvt_kcache_k<<<16384, 256, 0, stream>>>(kcache, Kall);
  // cached V: transpose+convert  (z = b*8+h; src base = b*4718592 + h*128)
  transpose_cvt_k<<<dim3(4, 128, 32), 256, 0, stream>>>(vcache, 4718592L, 128L, 1024,
                                                        VallT, 589824L, TOTAL_C);
  attn3_k<<<512, 256, 0, stream>>>(qrope, Kall, VallT, attno);
  // woT bf16 (4096x4096) = wo^T
  transpose_cvt_k<<<dim3(128, 128, 1), 256, 0, stream>>>(wo, 0L, 0L, 4096, woT, 0L, 4096);
  gemm_bt<1><<<dim3(32, 16), 256, 0, stream>>>(attno, woT, nullptr, out, x, 2048, 4096, 4096);
}